// Round 1
// 354.681 us; speedup vs baseline: 1.1869x; 1.1869x over previous
//
#include <hip/hip_runtime.h>
#include <hip/hip_bf16.h>

#define NN 262144
#define EPS 1e-8f

// ---- ws layout (float offsets) ----
#define WS_C      0            // c[512]
#define WS_K      512          // k[3*128]
#define WS_E      896          // e[128]
#define WS_A      1024         // a[128]
#define WS_KNSQ   1152         // |k|^2 [3]
#define WS_BETA   1155
#define WS_G      1158
#define WS_GAMMA  1161
#define WS_SL     1164         // shift logits [3*3] -> 1173
#define WS_ZC     1184         // FINAL: content denoms [3], prev denoms [3]
#define WS_SUMP   1190         // FINAL: sharpen sums [3]
#define WS_ZCR    1280         // 16 replicas x 32-stride: (zc0,zc1,zc2,zp0,zp1,zp2)
#define WS_SUMPR  1792         // 16 replicas x 32-stride: (sump0..2)
#define WS_RDACC  2304         // 8 replicas x 256: readings partials
#define WS_ZERO_CNT (WS_RDACC + 2048 - WS_KNSQ)   // zero 1152..4352
#define WS_T      4608         // t = exp(beta*sim) [3*NN]
#define WS_NEEDED ((size_t)(WS_T + 3 * NN) * 4)

// ---- d_out layout (FLOAT32 element offsets) ----
#define OUT_OUT   0
#define OUT_READ  256
#define OUT_RW    512
#define OUT_WW    (512 + 2 * NN)
#define OUT_MNEW  ((size_t)(512 + 3 * NN))

__global__ void FFNTM_78477642433000_kernel(int* p) { if (p) *p = 0; }

__device__ __forceinline__ float4 ld4(const float* p) { return *reinterpret_cast<const float4*>(p); }

__device__ __forceinline__ float wred(float v) {
#pragma unroll
    for (int off = 32; off > 0; off >>= 1) v += __shfl_xor(v, off);
    return v;
}

__device__ __forceinline__ void load_shift_params(const float* __restrict__ ws,
        float g[3], float gam[3], float izc[3], float izp[3],
        float s0[3], float s1[3], float s2[3]) {
#pragma unroll
    for (int h = 0; h < 3; h++) {
        g[h]   = ws[WS_G + h];
        gam[h] = ws[WS_GAMMA + h];
        izc[h] = 1.0f / fmaxf(ws[WS_ZC + h],     1e-30f);
        izp[h] = 1.0f / fmaxf(ws[WS_ZC + 3 + h], 1e-30f);
        const float l0 = ws[WS_SL + h*3], l1 = ws[WS_SL + h*3 + 1], l2 = ws[WS_SL + h*3 + 2];
        const float mx = fmaxf(l0, fmaxf(l1, l2));
        const float e0 = expf(l0 - mx), e1 = expf(l1 - mx), e2 = expf(l2 - mx);
        const float inv = 1.0f / (e0 + e1 + e2);
        s0[h] = e0 * inv; s1[h] = e1 * inv; s2[h] = e2 * inv;
    }
}

__global__ void csent(float* out, float val) {
    if (threadIdx.x == 0 && blockIdx.x == 0) out[OUT_OUT] = val;
}

// ---------------- c0: controller c = Wc @ [ext, prev_read] + bc; zero accumulators
__global__ void __launch_bounds__(256) c0(const float* __restrict__ ei, const float* __restrict__ pr,
                                          const float* __restrict__ Wc, const float* __restrict__ bc,
                                          float* __restrict__ ws) {
    const int t = threadIdx.x;
    const int lane = t & 63;
    const int j = (blockIdx.x * 256 + t) >> 6;   // wave per row, 0..511

    if (blockIdx.x == 0) {
        for (int i = t; i < WS_ZERO_CNT; i += 256) ws[WS_KNSQ + i] = 0.0f;
    }

    const float* xs = (lane < 32) ? (ei + lane * 8) : (pr + (lane - 32) * 8);
    const float4 xa = ld4(xs), xb = ld4(xs + 4);
    const float* wr = Wc + j * 512 + lane * 8;
    const float4 wa = ld4(wr), wb = ld4(wr + 4);
    float acc = xa.x * wa.x + xa.y * wa.y + xa.z * wa.z + xa.w * wa.w
              + xb.x * wb.x + xb.y * wb.y + xb.z * wb.z + xb.w * wb.w;
    acc = wred(acc);
    if (lane == 0) ws[WS_C + j] = acc + bc[j];
}

// ---------------- c1: all head parameters (C-order rows)
__global__ void __launch_bounds__(256) c1(
    const float* __restrict__ rWk, const float* __restrict__ rbk,
    const float* __restrict__ rWb, const float* __restrict__ rbb,
    const float* __restrict__ rWg, const float* __restrict__ rbg,
    const float* __restrict__ rWs, const float* __restrict__ rbs,
    const float* __restrict__ rWgm, const float* __restrict__ rbgm,
    const float* __restrict__ wWk, const float* __restrict__ wbk,
    const float* __restrict__ wWb, const float* __restrict__ wbb,
    const float* __restrict__ wWg, const float* __restrict__ wbg,
    const float* __restrict__ wWs, const float* __restrict__ wbs,
    const float* __restrict__ wWgm, const float* __restrict__ wbgm,
    const float* __restrict__ wWe, const float* __restrict__ wbe,
    const float* __restrict__ wWa, const float* __restrict__ wba,
    float* __restrict__ ws) {
    const int w = blockIdx.x * 4 + (threadIdx.x >> 6);
    const int lane = threadIdx.x & 63;
    if (w >= 658) return;

    const float4 ca = ld4(ws + WS_C + lane * 8);
    const float4 cb = ld4(ws + WS_C + lane * 8 + 4);

    const float* row; float bias; int kind; int h = 0, d = 0, sidx = 0;
    if (w < 384) {                        // keys: tanh
        h = w >> 7; d = w & 127;
        row  = (h < 2) ? (rWk + (h * 128 + d) * 512) : (wWk + d * 512);
        bias = (h < 2) ? rbk[h * 128 + d] : wbk[d];
        kind = 0;
    } else if (w < 512) {                 // erase: sigmoid
        d = w - 384; row = wWe + d * 512; bias = wbe[d]; kind = 1;
    } else if (w < 640) {                 // add: tanh
        d = w - 512; row = wWa + d * 512; bias = wba[d]; kind = 2;
    } else if (w < 643) {                 // beta: softplus
        h = w - 640; row = (h < 2) ? (rWb + h * 512) : wWb;
        bias = (h < 2) ? rbb[h] : wbb[0]; kind = 3;
    } else if (w < 646) {                 // g: sigmoid
        h = w - 643; row = (h < 2) ? (rWg + h * 512) : wWg;
        bias = (h < 2) ? rbg[h] : wbg[0]; kind = 4;
    } else if (w < 649) {                 // gamma: 1+softplus
        h = w - 646; row = (h < 2) ? (rWgm + h * 512) : wWgm;
        bias = (h < 2) ? rbgm[h] : wbgm[0]; kind = 5;
    } else {                              // shift logits
        sidx = w - 649; h = sidx / 3; const int jj = sidx % 3;
        row  = (h < 2) ? (rWs + (h * 3 + jj) * 512) : (wWs + jj * 512);
        bias = (h < 2) ? rbs[h * 3 + jj] : wbs[jj];
        kind = 6;
    }

    const float4 ra = ld4(row + lane * 8);
    const float4 rb = ld4(row + lane * 8 + 4);
    float acc = ca.x * ra.x + ca.y * ra.y + ca.z * ra.z + ca.w * ra.w
              + cb.x * rb.x + cb.y * rb.y + cb.z * rb.z + cb.w * rb.w;
    acc = wred(acc);

    if (lane == 0) {
        const float x = acc + bias;
        switch (kind) {
            case 0: { float kv = tanhf(x); ws[WS_K + w] = kv; atomicAdd(&ws[WS_KNSQ + h], kv * kv); } break;
            case 1: ws[WS_E + d] = 1.0f / (1.0f + expf(-x)); break;
            case 2: ws[WS_A + d] = tanhf(x); break;
            case 3: ws[WS_BETA + h] = log1pf(expf(x)); break;
            case 4: ws[WS_G + h] = 1.0f / (1.0f + expf(-x)); break;
            case 5: ws[WS_GAMMA + h] = 1.0f + log1pf(expf(x)); break;
            case 6: ws[WS_SL + sidx] = x; break;
        }
    }
}

// ---------------- c2: content scores t=exp(beta*cos_sim); exp(init) scratch; denom partials
__global__ void __launch_bounds__(256) c2(const float* __restrict__ M, const float* __restrict__ rinit,
                                          const float* __restrict__ winit, float* __restrict__ out,
                                          float* __restrict__ ws) {
    const int t = threadIdx.x;
    const int lane = t & 63;
    const int wv = t >> 6;
    const int grp = t >> 5;          // 32-lane group = one memory row
    const int sub = lane & 31;

    float kf0[4], kf1[4], kf2[4];
#pragma unroll
    for (int j = 0; j < 4; j++) {
        kf0[j] = ws[WS_K +       sub * 4 + j];
        kf1[j] = ws[WS_K + 128 + sub * 4 + j];
        kf2[j] = ws[WS_K + 256 + sub * 4 + j];
    }
    float beta[3], kn[3];
#pragma unroll
    for (int h = 0; h < 3; h++) { kn[h] = sqrtf(ws[WS_KNSQ + h]); beta[h] = ws[WS_BETA + h]; }

    float zc0 = 0, zc1 = 0, zc2 = 0, zp0 = 0, zp1 = 0, zp2 = 0;

    for (int row = blockIdx.x * 8 + grp; row < NN; row += gridDim.x * 8) {
        const float4 m = ld4(M + (size_t)row * 128 + sub * 4);
        float d0 = m.x * kf0[0] + m.y * kf0[1] + m.z * kf0[2] + m.w * kf0[3];
        float d1 = m.x * kf1[0] + m.y * kf1[1] + m.z * kf1[2] + m.w * kf1[3];
        float d2 = m.x * kf2[0] + m.y * kf2[1] + m.z * kf2[2] + m.w * kf2[3];
        float ns = m.x * m.x + m.y * m.y + m.z * m.z + m.w * m.w;
#pragma unroll
        for (int off = 1; off < 32; off <<= 1) {
            d0 += __shfl_xor(d0, off);
            d1 += __shfl_xor(d1, off);
            d2 += __shfl_xor(d2, off);
            ns += __shfl_xor(ns, off);
        }
        if (sub == 0) {
            const float mn = sqrtf(ns);
            const float t0 = expf(beta[0] * d0 / (mn * kn[0] + EPS));
            const float t1 = expf(beta[1] * d1 / (mn * kn[1] + EPS));
            const float t2 = expf(beta[2] * d2 / (mn * kn[2] + EPS));
            ws[WS_T + row]          = t0;
            ws[WS_T + NN + row]     = t1;
            ws[WS_T + 2 * NN + row] = t2;
            zc0 += t0; zc1 += t1; zc2 += t2;
        }
    }

    // prev-weighting exps: compute once, STORE for c3 (scratch inside out's M_new region)
    float* Esc = out + OUT_MNEW;
    for (int i = blockIdx.x * 256 + t; i < NN; i += gridDim.x * 256) {
        const float e0 = expf(rinit[i]);
        const float e1 = expf(rinit[NN + i]);
        const float e2 = expf(winit[i]);
        Esc[i]          = e0;
        Esc[NN + i]     = e1;
        Esc[2 * NN + i] = e2;
        zp0 += e0; zp1 += e1; zp2 += e2;
    }

    __shared__ float red[4][6];
    float vals[6] = {zc0, zc1, zc2, zp0, zp1, zp2};
#pragma unroll
    for (int q = 0; q < 6; q++) {
        float v = wred(vals[q]);
        if (lane == 0) red[wv][q] = v;
    }
    __syncthreads();
    if (t < 6) {
        // padded replica slot (bid&15): 128B apart -> no same-line pileup
        atomicAdd(&ws[WS_ZCR + (blockIdx.x & 15) * 32 + t],
                  red[0][t] + red[1][t] + red[2][t] + red[3][t]);
    }
}

// ---------------- c2b: finalize denominators (16 replicas -> WS_ZC)
__global__ void c2b(float* __restrict__ ws) {
    const int t = threadIdx.x;
    if (t < 6) {
        float s = 0.0f;
#pragma unroll
        for (int r = 0; r < 16; r++) s += ws[WS_ZCR + r * 32 + t];
        ws[WS_ZC + t] = s;
    }
}

// ---------------- c3: sharpened unnormalized weights p -> out slots; sharpen-sum partials
__global__ void __launch_bounds__(256) c3(float* __restrict__ out, float* __restrict__ ws) {
    float g[3], gam[3], izc[3], izp[3], s0[3], s1[3], s2[3];
    load_shift_params(ws, g, gam, izc, izp, s0, s1, s2);
    const float* Esc = out + OUT_MNEW;

    float sump[3] = {0.f, 0.f, 0.f};
    for (int i = blockIdx.x * 256 + threadIdx.x; i < NN; i += gridDim.x * 256) {
        const int im = (i == 0) ? (NN - 1) : (i - 1);
        const int ip = (i == NN - 1) ? 0 : (i + 1);
#pragma unroll
        for (int h = 0; h < 3; h++) {
            const float* tp = ws + WS_T + h * NN;
            const float* Ep = Esc + (size_t)h * NN;
            const float gg = g[h], om = 1.0f - gg;
            const float wgm = gg * tp[im] * izc[h] + om * Ep[im] * izp[h];
            const float wg0 = gg * tp[i]  * izc[h] + om * Ep[i]  * izp[h];
            const float wgp = gg * tp[ip] * izc[h] + om * Ep[ip] * izp[h];
            const float wt = fmaxf(s0[h] * wgp + s1[h] * wg0 + s2[h] * wgm, 1e-30f);
            const float p = expf(gam[h] * logf(wt));
            sump[h] += p;
            float* pd = (h == 0) ? (out + OUT_RW) : (h == 1) ? (out + OUT_RW + NN) : (out + OUT_WW);
            pd[i] = p;   // unnormalized; c4 rescales in place
        }
    }

    __shared__ float red[4][3];
    const int lane = threadIdx.x & 63, wv = threadIdx.x >> 6;
#pragma unroll
    for (int h = 0; h < 3; h++) {
        float v = wred(sump[h]);
        if (lane == 0) red[wv][h] = v;
    }
    __syncthreads();
    if (threadIdx.x < 3) {
        atomicAdd(&ws[WS_SUMPR + (blockIdx.x & 15) * 32 + threadIdx.x],
                  red[0][threadIdx.x] + red[1][threadIdx.x] + red[2][threadIdx.x] + red[3][threadIdx.x]);
    }
}

// ---------------- c3b: finalize sharpen sums (16 replicas -> WS_SUMP)
__global__ void c3b(float* __restrict__ ws) {
    const int t = threadIdx.x;
    if (t < 3) {
        float s = 0.0f;
#pragma unroll
        for (int r = 0; r < 16; r++) s += ws[WS_SUMPR + r * 32 + t];
        ws[WS_SUMP + t] = s;
    }
}

// ---------------- c4: pure streaming — normalize weights in place, M_new, readings partials
__global__ void __launch_bounds__(256) c4(const float* __restrict__ M, float* __restrict__ out,
                                          float* __restrict__ ws) {
    float isp[3];
#pragma unroll
    for (int h = 0; h < 3; h++) isp[h] = 1.0f / (ws[WS_SUMP + h] + EPS);

    const int t = threadIdx.x;
    const int lane = t & 63;
    const int wv = t >> 6;
    const int grp = t >> 5;
    const int sub = lane & 31;

    float ev[4], av[4];
#pragma unroll
    for (int j = 0; j < 4; j++) { ev[j] = ws[WS_E + sub * 4 + j]; av[j] = ws[WS_A + sub * 4 + j]; }

    float r0[4] = {0, 0, 0, 0}, r1[4] = {0, 0, 0, 0};

    for (int row = blockIdx.x * 8 + grp; row < NN; row += gridDim.x * 8) {
        // broadcast loads (same address across the 32-lane group)
        const float w0 = out[OUT_RW + row]      * isp[0];
        const float w1 = out[OUT_RW + NN + row] * isp[1];
        const float w2 = out[OUT_WW + row]      * isp[2];
        const float4 m = ld4(M + (size_t)row * 128 + sub * 4);
        float4 nv;
        nv.x = m.x * (1.0f - w2 * ev[0]) + w2 * av[0];
        nv.y = m.y * (1.0f - w2 * ev[1]) + w2 * av[1];
        nv.z = m.z * (1.0f - w2 * ev[2]) + w2 * av[2];
        nv.w = m.w * (1.0f - w2 * ev[3]) + w2 * av[3];
        *reinterpret_cast<float4*>(out + OUT_MNEW + (size_t)row * 128 + sub * 4) = nv;
        r0[0] += w0 * m.x; r0[1] += w0 * m.y; r0[2] += w0 * m.z; r0[3] += w0 * m.w;
        r1[0] += w1 * m.x; r1[1] += w1 * m.y; r1[2] += w1 * m.z; r1[3] += w1 * m.w;
        if (sub == 0) {
            out[OUT_RW + row]      = w0;
            out[OUT_RW + NN + row] = w1;
            out[OUT_WW + row]      = w2;
        }
    }

#pragma unroll
    for (int j = 0; j < 4; j++) {
        r0[j] += __shfl_xor(r0[j], 32);
        r1[j] += __shfl_xor(r1[j], 32);
    }
    __shared__ float lds[4][256];
    if (lane < 32) {
#pragma unroll
        for (int j = 0; j < 4; j++) {
            lds[wv][sub * 4 + j]       = r0[j];
            lds[wv][128 + sub * 4 + j] = r1[j];
        }
    }
    __syncthreads();
    atomicAdd(&ws[WS_RDACC + (blockIdx.x & 7) * 256 + t],
              lds[0][t] + lds[1][t] + lds[2][t] + lds[3][t]);
}

// ---------------- c5: out = Wo @ [c, readings] + bo; emit readings (f32)
__global__ void __launch_bounds__(256) c5(const float* __restrict__ Wo, const float* __restrict__ bo,
                                          float* __restrict__ ws, float* __restrict__ out) {
    __shared__ float rd[256];
    const int t = threadIdx.x;
    {
        float s = 0.0f;
#pragma unroll
        for (int r = 0; r < 8; r++) s += ws[WS_RDACC + r * 256 + t];
        rd[t] = s;
    }
    __syncthreads();

    const int lane = t & 63;
    const int j = blockIdx.x * 4 + (t >> 6);   // 0..255
    const float* row = Wo + j * 768;
    float acc = 0.0f;
#pragma unroll
    for (int q = 0; q < 12; q++) {
        const int i = lane * 12 + q;
        const float x = (i < 512) ? ws[WS_C + i] : rd[i - 512];
        acc += row[i] * x;
    }
    acc = wred(acc);
    if (lane == 0) out[OUT_OUT + j] = acc + bo[j];
    if (blockIdx.x == 0) out[OUT_READ + t] = rd[t];
}

extern "C" void kernel_launch(void* const* d_in, const int* in_sizes, int n_in,
                              void* d_out, int out_size, void* d_ws, size_t ws_size,
                              hipStream_t stream) {
    float* out = (float*)d_out;

    static const int expect[33] = {
        256, 33554432, 256, 262144, 512, 196608, 256,
        131072, 256, 1024, 2, 1024, 2, 3072, 6, 1024, 2, 524288,
        65536, 128, 512, 1, 512, 1, 1536, 3, 512, 1,
        65536, 128, 65536, 128, 262144
    };
    int bad = (n_in == 33) ? -1 : 33;
    if (bad < 0) {
        for (int i = 0; i < 33; i++) {
            if (in_sizes[i] != expect[i]) { bad = i; break; }
        }
    }
    if (bad >= 0) { csent<<<1, 64, 0, stream>>>(out, 10000.0f + (float)bad); return; }
    if (ws_size < WS_NEEDED) { csent<<<1, 64, 0, stream>>>(out, 5000.0f + (float)(ws_size >> 20)); return; }

    const float* ei    = (const float*)d_in[0];
    const float* M     = (const float*)d_in[1];
    const float* pr    = (const float*)d_in[2];
    const float* Wc    = (const float*)d_in[3];
    const float* bc    = (const float*)d_in[4];
    const float* Wo    = (const float*)d_in[5];
    const float* bo    = (const float*)d_in[6];
    const float* rWk   = (const float*)d_in[7];
    const float* rbk   = (const float*)d_in[8];
    const float* rWb   = (const float*)d_in[9];
    const float* rbb   = (const float*)d_in[10];
    const float* rWg   = (const float*)d_in[11];
    const float* rbg   = (const float*)d_in[12];
    const float* rWs   = (const float*)d_in[13];
    const float* rbs   = (const float*)d_in[14];
    const float* rWgm  = (const float*)d_in[15];
    const float* rbgm  = (const float*)d_in[16];
    const float* rinit = (const float*)d_in[17];
    const float* wWk   = (const float*)d_in[18];
    const float* wbk   = (const float*)d_in[19];
    const float* wWb   = (const float*)d_in[20];
    const float* wbb   = (const float*)d_in[21];
    const float* wWg   = (const float*)d_in[22];
    const float* wbg   = (const float*)d_in[23];
    const float* wWs   = (const float*)d_in[24];
    const float* wbs   = (const float*)d_in[25];
    const float* wWgm  = (const float*)d_in[26];
    const float* wbgm  = (const float*)d_in[27];
    const float* wWe   = (const float*)d_in[28];
    const float* wbe   = (const float*)d_in[29];
    const float* wWa   = (const float*)d_in[30];
    const float* wba   = (const float*)d_in[31];
    const float* winit = (const float*)d_in[32];
    float* ws = (float*)d_ws;

    c0<<<128, 256, 0, stream>>>(ei, pr, Wc, bc, ws);
    c1<<<165, 256, 0, stream>>>(rWk, rbk, rWb, rbb, rWg, rbg, rWs, rbs, rWgm, rbgm,
                                wWk, wbk, wWb, wbb, wWg, wbg, wWs, wbs, wWgm, wbgm,
                                wWe, wbe, wWa, wba, ws);
    c2<<<2048, 256, 0, stream>>>(M, rinit, winit, out, ws);
    c2b<<<1, 64, 0, stream>>>(ws);
    c3<<<1024, 256, 0, stream>>>(out, ws);
    c3b<<<1, 64, 0, stream>>>(ws);
    c4<<<1024, 256, 0, stream>>>(M, out, ws);
    c5<<<64, 256, 0, stream>>>(Wo, bo, ws, out);
}

// Round 2
// 349.409 us; speedup vs baseline: 1.2048x; 1.0151x over previous
//
#include <hip/hip_runtime.h>
#include <hip/hip_bf16.h>

#define NN 262144
#define EPS 1e-8f

// ---- ws layout (float offsets) ----
#define WS_C      0            // c[512]
#define WS_K      512          // k[3*128]
#define WS_E      896          // e[128]
#define WS_A      1024         // a[128]
#define WS_KNSQ   1152         // |k|^2 [3]
#define WS_BETA   1155
#define WS_G      1158
#define WS_GAMMA  1161
#define WS_SL     1164         // shift logits [3*3] -> 1173
#define WS_ZCR    1280         // 16 replicas x 32-stride: (zc0,zc1,zc2,zp0,zp1,zp2)
#define WS_SUMPR  1792         // 16 replicas x 32-stride: (sump0..2)
#define WS_RDACC  2304         // 8 replicas x 256: readings partials
#define WS_ZERO_CNT (WS_RDACC + 2048 - WS_KNSQ)   // zero 1152..4352
#define WS_T      4608         // t = exp(beta*sim) [3*NN]
#define WS_NEEDED ((size_t)(WS_T + 3 * NN) * 4)

// ---- d_out layout (FLOAT32 element offsets) ----
#define OUT_OUT   0
#define OUT_READ  256
#define OUT_RW    512
#define OUT_WW    (512 + 2 * NN)
#define OUT_MNEW  ((size_t)(512 + 3 * NN))

__global__ void FFNTM_78477642433000_kernel(int* p) { if (p) *p = 0; }

__device__ __forceinline__ float4 ld4(const float* p) { return *reinterpret_cast<const float4*>(p); }

__device__ __forceinline__ float wred(float v) {
#pragma unroll
    for (int off = 32; off > 0; off >>= 1) v += __shfl_xor(v, off);
    return v;
}

// sums the 16 ZCR replicas (c2b folded in) and builds all shift params
__device__ __forceinline__ void load_shift_params(const float* __restrict__ ws,
        float g[3], float gam[3], float izc[3], float izp[3],
        float s0[3], float s1[3], float s2[3]) {
#pragma unroll
    for (int h = 0; h < 3; h++) {
        float zc = 0.0f, zp = 0.0f;
#pragma unroll
        for (int r = 0; r < 16; r++) {
            zc += ws[WS_ZCR + r * 32 + h];
            zp += ws[WS_ZCR + r * 32 + 3 + h];
        }
        g[h]   = ws[WS_G + h];
        gam[h] = ws[WS_GAMMA + h];
        izc[h] = 1.0f / fmaxf(zc, 1e-30f);
        izp[h] = 1.0f / fmaxf(zp, 1e-30f);
        const float l0 = ws[WS_SL + h*3], l1 = ws[WS_SL + h*3 + 1], l2 = ws[WS_SL + h*3 + 2];
        const float mx = fmaxf(l0, fmaxf(l1, l2));
        const float e0 = expf(l0 - mx), e1 = expf(l1 - mx), e2 = expf(l2 - mx);
        const float inv = 1.0f / (e0 + e1 + e2);
        s0[h] = e0 * inv; s1[h] = e1 * inv; s2[h] = e2 * inv;
    }
}

__global__ void csent(float* out, float val) {
    if (threadIdx.x == 0 && blockIdx.x == 0) out[OUT_OUT] = val;
}

// ---------------- c0: controller c = Wc @ [ext, prev_read] + bc; zero accumulators
__global__ void __launch_bounds__(256) c0(const float* __restrict__ ei, const float* __restrict__ pr,
                                          const float* __restrict__ Wc, const float* __restrict__ bc,
                                          float* __restrict__ ws) {
    const int t = threadIdx.x;
    const int lane = t & 63;
    const int j = (blockIdx.x * 256 + t) >> 6;   // wave per row, 0..511

    if (blockIdx.x == 0) {
        for (int i = t; i < WS_ZERO_CNT; i += 256) ws[WS_KNSQ + i] = 0.0f;
    }

    const float* xs = (lane < 32) ? (ei + lane * 8) : (pr + (lane - 32) * 8);
    const float4 xa = ld4(xs), xb = ld4(xs + 4);
    const float* wr = Wc + j * 512 + lane * 8;
    const float4 wa = ld4(wr), wb = ld4(wr + 4);
    float acc = xa.x * wa.x + xa.y * wa.y + xa.z * wa.z + xa.w * wa.w
              + xb.x * wb.x + xb.y * wb.y + xb.z * wb.z + xb.w * wb.w;
    acc = wred(acc);
    if (lane == 0) ws[WS_C + j] = acc + bc[j];
}

// ---------------- c1: all head parameters (C-order rows)
__global__ void __launch_bounds__(256) c1(
    const float* __restrict__ rWk, const float* __restrict__ rbk,
    const float* __restrict__ rWb, const float* __restrict__ rbb,
    const float* __restrict__ rWg, const float* __restrict__ rbg,
    const float* __restrict__ rWs, const float* __restrict__ rbs,
    const float* __restrict__ rWgm, const float* __restrict__ rbgm,
    const float* __restrict__ wWk, const float* __restrict__ wbk,
    const float* __restrict__ wWb, const float* __restrict__ wbb,
    const float* __restrict__ wWg, const float* __restrict__ wbg,
    const float* __restrict__ wWs, const float* __restrict__ wbs,
    const float* __restrict__ wWgm, const float* __restrict__ wbgm,
    const float* __restrict__ wWe, const float* __restrict__ wbe,
    const float* __restrict__ wWa, const float* __restrict__ wba,
    float* __restrict__ ws) {
    const int w = blockIdx.x * 4 + (threadIdx.x >> 6);
    const int lane = threadIdx.x & 63;
    if (w >= 658) return;

    const float4 ca = ld4(ws + WS_C + lane * 8);
    const float4 cb = ld4(ws + WS_C + lane * 8 + 4);

    const float* row; float bias; int kind; int h = 0, d = 0, sidx = 0;
    if (w < 384) {                        // keys: tanh
        h = w >> 7; d = w & 127;
        row  = (h < 2) ? (rWk + (h * 128 + d) * 512) : (wWk + d * 512);
        bias = (h < 2) ? rbk[h * 128 + d] : wbk[d];
        kind = 0;
    } else if (w < 512) {                 // erase: sigmoid
        d = w - 384; row = wWe + d * 512; bias = wbe[d]; kind = 1;
    } else if (w < 640) {                 // add: tanh
        d = w - 512; row = wWa + d * 512; bias = wba[d]; kind = 2;
    } else if (w < 643) {                 // beta: softplus
        h = w - 640; row = (h < 2) ? (rWb + h * 512) : wWb;
        bias = (h < 2) ? rbb[h] : wbb[0]; kind = 3;
    } else if (w < 646) {                 // g: sigmoid
        h = w - 643; row = (h < 2) ? (rWg + h * 512) : wWg;
        bias = (h < 2) ? rbg[h] : wbg[0]; kind = 4;
    } else if (w < 649) {                 // gamma: 1+softplus
        h = w - 646; row = (h < 2) ? (rWgm + h * 512) : wWgm;
        bias = (h < 2) ? rbgm[h] : wbgm[0]; kind = 5;
    } else {                              // shift logits
        sidx = w - 649; h = sidx / 3; const int jj = sidx % 3;
        row  = (h < 2) ? (rWs + (h * 3 + jj) * 512) : (wWs + jj * 512);
        bias = (h < 2) ? rbs[h * 3 + jj] : wbs[jj];
        kind = 6;
    }

    const float4 ra = ld4(row + lane * 8);
    const float4 rb = ld4(row + lane * 8 + 4);
    float acc = ca.x * ra.x + ca.y * ra.y + ca.z * ra.z + ca.w * ra.w
              + cb.x * rb.x + cb.y * rb.y + cb.z * rb.z + cb.w * rb.w;
    acc = wred(acc);

    if (lane == 0) {
        const float x = acc + bias;
        switch (kind) {
            case 0: { float kv = tanhf(x); ws[WS_K + w] = kv; atomicAdd(&ws[WS_KNSQ + h], kv * kv); } break;
            case 1: ws[WS_E + d] = 1.0f / (1.0f + expf(-x)); break;
            case 2: ws[WS_A + d] = tanhf(x); break;
            case 3: ws[WS_BETA + h] = log1pf(expf(x)); break;
            case 4: ws[WS_G + h] = 1.0f / (1.0f + expf(-x)); break;
            case 5: ws[WS_GAMMA + h] = 1.0f + log1pf(expf(x)); break;
            case 6: ws[WS_SL + sidx] = x; break;
        }
    }
}

// ---------------- c2: content scores t=exp(beta*cos_sim); exp(init) scratch; denom partials
// 8 lanes per row (16 contiguous floats each): 3-level reduce, expf issued once per 8 rows.
__global__ void __launch_bounds__(256) c2(const float* __restrict__ M, const float* __restrict__ rinit,
                                          const float* __restrict__ winit, float* __restrict__ out,
                                          float* __restrict__ ws) {
    const int t = threadIdx.x;
    const int lane = t & 63;
    const int wv = t >> 6;           // wave in block, 0..3
    const int rl = lane >> 3;        // row within wave's batch of 8
    const int cl = lane & 7;         // 16-float column slice

    float kf0[16], kf1[16], kf2[16];
#pragma unroll
    for (int j = 0; j < 16; j++) {
        kf0[j] = ws[WS_K +       cl * 16 + j];
        kf1[j] = ws[WS_K + 128 + cl * 16 + j];
        kf2[j] = ws[WS_K + 256 + cl * 16 + j];
    }
    float beta[3], kn[3];
#pragma unroll
    for (int h = 0; h < 3; h++) { kn[h] = sqrtf(ws[WS_KNSQ + h]); beta[h] = ws[WS_BETA + h]; }

    float zc0 = 0, zc1 = 0, zc2 = 0, zp0 = 0, zp1 = 0, zp2 = 0;

    // block covers 32 rows per iteration (4 waves x 8 rows)
    for (int row = blockIdx.x * 32 + wv * 8 + rl; row < NN; row += gridDim.x * 32) {
        const float* mp = M + (size_t)row * 128 + cl * 16;
        float d0 = 0, d1 = 0, d2 = 0, ns = 0;
#pragma unroll
        for (int q = 0; q < 4; q++) {
            const float4 m = ld4(mp + q * 4);
            d0 += m.x * kf0[q*4+0] + m.y * kf0[q*4+1] + m.z * kf0[q*4+2] + m.w * kf0[q*4+3];
            d1 += m.x * kf1[q*4+0] + m.y * kf1[q*4+1] + m.z * kf1[q*4+2] + m.w * kf1[q*4+3];
            d2 += m.x * kf2[q*4+0] + m.y * kf2[q*4+1] + m.z * kf2[q*4+2] + m.w * kf2[q*4+3];
            ns += m.x * m.x + m.y * m.y + m.z * m.z + m.w * m.w;
        }
#pragma unroll
        for (int off = 1; off < 8; off <<= 1) {
            d0 += __shfl_xor(d0, off);
            d1 += __shfl_xor(d1, off);
            d2 += __shfl_xor(d2, off);
            ns += __shfl_xor(ns, off);
        }
        if (cl == 0) {
            const float mn = sqrtf(ns);
            const float t0 = expf(beta[0] * d0 / (mn * kn[0] + EPS));
            const float t1 = expf(beta[1] * d1 / (mn * kn[1] + EPS));
            const float t2 = expf(beta[2] * d2 / (mn * kn[2] + EPS));
            ws[WS_T + row]          = t0;
            ws[WS_T + NN + row]     = t1;
            ws[WS_T + 2 * NN + row] = t2;
            zc0 += t0; zc1 += t1; zc2 += t2;
        }
    }

    // prev-weighting exps: compute once, STORE for c3 (scratch inside out's M_new region)
    float* Esc = out + OUT_MNEW;
    for (int i = blockIdx.x * 256 + t; i < NN; i += gridDim.x * 256) {
        const float e0 = expf(rinit[i]);
        const float e1 = expf(rinit[NN + i]);
        const float e2 = expf(winit[i]);
        Esc[i]          = e0;
        Esc[NN + i]     = e1;
        Esc[2 * NN + i] = e2;
        zp0 += e0; zp1 += e1; zp2 += e2;
    }

    __shared__ float red[4][6];
    float vals[6] = {zc0, zc1, zc2, zp0, zp1, zp2};
#pragma unroll
    for (int q = 0; q < 6; q++) {
        float v = wred(vals[q]);
        if (lane == 0) red[wv][q] = v;
    }
    __syncthreads();
    if (t < 6) {
        // padded replica slot (bid&15): 128B apart -> no same-line pileup
        atomicAdd(&ws[WS_ZCR + (blockIdx.x & 15) * 32 + t],
                  red[0][t] + red[1][t] + red[2][t] + red[3][t]);
    }
}

// ---------------- c3: sharpened unnormalized weights p -> out slots; sharpen-sum partials
__global__ void __launch_bounds__(256) c3(float* __restrict__ out, float* __restrict__ ws) {
    float g[3], gam[3], izc[3], izp[3], s0[3], s1[3], s2[3];
    load_shift_params(ws, g, gam, izc, izp, s0, s1, s2);
    const float* Esc = out + OUT_MNEW;

    float sump[3] = {0.f, 0.f, 0.f};
    for (int i = blockIdx.x * 256 + threadIdx.x; i < NN; i += gridDim.x * 256) {
        const int im = (i == 0) ? (NN - 1) : (i - 1);
        const int ip = (i == NN - 1) ? 0 : (i + 1);
#pragma unroll
        for (int h = 0; h < 3; h++) {
            const float* tp = ws + WS_T + h * NN;
            const float* Ep = Esc + (size_t)h * NN;
            const float gg = g[h], om = 1.0f - gg;
            const float wgm = gg * tp[im] * izc[h] + om * Ep[im] * izp[h];
            const float wg0 = gg * tp[i]  * izc[h] + om * Ep[i]  * izp[h];
            const float wgp = gg * tp[ip] * izc[h] + om * Ep[ip] * izp[h];
            const float wt = fmaxf(s0[h] * wgp + s1[h] * wg0 + s2[h] * wgm, 1e-30f);
            const float p = expf(gam[h] * logf(wt));
            sump[h] += p;
            float* pd = (h == 0) ? (out + OUT_RW) : (h == 1) ? (out + OUT_RW + NN) : (out + OUT_WW);
            pd[i] = p;   // unnormalized; c4 rescales in place
        }
    }

    __shared__ float red[4][3];
    const int lane = threadIdx.x & 63, wv = threadIdx.x >> 6;
#pragma unroll
    for (int h = 0; h < 3; h++) {
        float v = wred(sump[h]);
        if (lane == 0) red[wv][h] = v;
    }
    __syncthreads();
    if (threadIdx.x < 3) {
        atomicAdd(&ws[WS_SUMPR + (blockIdx.x & 15) * 32 + threadIdx.x],
                  red[0][threadIdx.x] + red[1][threadIdx.x] + red[2][threadIdx.x] + red[3][threadIdx.x]);
    }
}

// ---------------- c4: pure streaming — normalize weights in place, M_new, readings partials
// (c3b folded in: sums the 16 SUMPR replicas directly)
__global__ void __launch_bounds__(256) c4(const float* __restrict__ M, float* __restrict__ out,
                                          float* __restrict__ ws) {
    float isp[3];
#pragma unroll
    for (int h = 0; h < 3; h++) {
        float s = 0.0f;
#pragma unroll
        for (int r = 0; r < 16; r++) s += ws[WS_SUMPR + r * 32 + h];
        isp[h] = 1.0f / (s + EPS);
    }

    const int t = threadIdx.x;
    const int lane = t & 63;
    const int wv = t >> 6;
    const int grp = t >> 5;
    const int sub = lane & 31;

    float ev[4], av[4];
#pragma unroll
    for (int j = 0; j < 4; j++) { ev[j] = ws[WS_E + sub * 4 + j]; av[j] = ws[WS_A + sub * 4 + j]; }

    float r0[4] = {0, 0, 0, 0}, r1[4] = {0, 0, 0, 0};

    for (int row = blockIdx.x * 8 + grp; row < NN; row += gridDim.x * 8) {
        // broadcast loads (same address across the 32-lane group)
        const float w0 = out[OUT_RW + row]      * isp[0];
        const float w1 = out[OUT_RW + NN + row] * isp[1];
        const float w2 = out[OUT_WW + row]      * isp[2];
        const float4 m = ld4(M + (size_t)row * 128 + sub * 4);
        float4 nv;
        nv.x = m.x * (1.0f - w2 * ev[0]) + w2 * av[0];
        nv.y = m.y * (1.0f - w2 * ev[1]) + w2 * av[1];
        nv.z = m.z * (1.0f - w2 * ev[2]) + w2 * av[2];
        nv.w = m.w * (1.0f - w2 * ev[3]) + w2 * av[3];
        *reinterpret_cast<float4*>(out + OUT_MNEW + (size_t)row * 128 + sub * 4) = nv;
        r0[0] += w0 * m.x; r0[1] += w0 * m.y; r0[2] += w0 * m.z; r0[3] += w0 * m.w;
        r1[0] += w1 * m.x; r1[1] += w1 * m.y; r1[2] += w1 * m.z; r1[3] += w1 * m.w;
        if (sub == 0) {
            out[OUT_RW + row]      = w0;
            out[OUT_RW + NN + row] = w1;
            out[OUT_WW + row]      = w2;
        }
    }

#pragma unroll
    for (int j = 0; j < 4; j++) {
        r0[j] += __shfl_xor(r0[j], 32);
        r1[j] += __shfl_xor(r1[j], 32);
    }
    __shared__ float lds[4][256];
    if (lane < 32) {
#pragma unroll
        for (int j = 0; j < 4; j++) {
            lds[wv][sub * 4 + j]       = r0[j];
            lds[wv][128 + sub * 4 + j] = r1[j];
        }
    }
    __syncthreads();
    atomicAdd(&ws[WS_RDACC + (blockIdx.x & 7) * 256 + t],
              lds[0][t] + lds[1][t] + lds[2][t] + lds[3][t]);
}

// ---------------- c5: out = Wo @ [c, readings] + bo; emit readings (f32)
__global__ void __launch_bounds__(256) c5(const float* __restrict__ Wo, const float* __restrict__ bo,
                                          float* __restrict__ ws, float* __restrict__ out) {
    __shared__ float rd[256];
    const int t = threadIdx.x;
    {
        float s = 0.0f;
#pragma unroll
        for (int r = 0; r < 8; r++) s += ws[WS_RDACC + r * 256 + t];
        rd[t] = s;
    }
    __syncthreads();

    const int lane = t & 63;
    const int j = blockIdx.x * 4 + (t >> 6);   // 0..255
    const float* row = Wo + j * 768;
    float acc = 0.0f;
#pragma unroll
    for (int q = 0; q < 12; q++) {
        const int i = lane * 12 + q;
        const float x = (i < 512) ? ws[WS_C + i] : rd[i - 512];
        acc += row[i] * x;
    }
    acc = wred(acc);
    if (lane == 0) out[OUT_OUT + j] = acc + bo[j];
    if (blockIdx.x == 0) out[OUT_READ + t] = rd[t];
}

extern "C" void kernel_launch(void* const* d_in, const int* in_sizes, int n_in,
                              void* d_out, int out_size, void* d_ws, size_t ws_size,
                              hipStream_t stream) {
    float* out = (float*)d_out;

    static const int expect[33] = {
        256, 33554432, 256, 262144, 512, 196608, 256,
        131072, 256, 1024, 2, 1024, 2, 3072, 6, 1024, 2, 524288,
        65536, 128, 512, 1, 512, 1, 1536, 3, 512, 1,
        65536, 128, 65536, 128, 262144
    };
    int bad = (n_in == 33) ? -1 : 33;
    if (bad < 0) {
        for (int i = 0; i < 33; i++) {
            if (in_sizes[i] != expect[i]) { bad = i; break; }
        }
    }
    if (bad >= 0) { csent<<<1, 64, 0, stream>>>(out, 10000.0f + (float)bad); return; }
    if (ws_size < WS_NEEDED) { csent<<<1, 64, 0, stream>>>(out, 5000.0f + (float)(ws_size >> 20)); return; }

    const float* ei    = (const float*)d_in[0];
    const float* M     = (const float*)d_in[1];
    const float* pr    = (const float*)d_in[2];
    const float* Wc    = (const float*)d_in[3];
    const float* bc    = (const float*)d_in[4];
    const float* Wo    = (const float*)d_in[5];
    const float* bo    = (const float*)d_in[6];
    const float* rWk   = (const float*)d_in[7];
    const float* rbk   = (const float*)d_in[8];
    const float* rWb   = (const float*)d_in[9];
    const float* rbb   = (const float*)d_in[10];
    const float* rWg   = (const float*)d_in[11];
    const float* rbg   = (const float*)d_in[12];
    const float* rWs   = (const float*)d_in[13];
    const float* rbs   = (const float*)d_in[14];
    const float* rWgm  = (const float*)d_in[15];
    const float* rbgm  = (const float*)d_in[16];
    const float* rinit = (const float*)d_in[17];
    const float* wWk   = (const float*)d_in[18];
    const float* wbk   = (const float*)d_in[19];
    const float* wWb   = (const float*)d_in[20];
    const float* wbb   = (const float*)d_in[21];
    const float* wWg   = (const float*)d_in[22];
    const float* wbg   = (const float*)d_in[23];
    const float* wWs   = (const float*)d_in[24];
    const float* wbs   = (const float*)d_in[25];
    const float* wWgm  = (const float*)d_in[26];
    const float* wbgm  = (const float*)d_in[27];
    const float* wWe   = (const float*)d_in[28];
    const float* wbe   = (const float*)d_in[29];
    const float* wWa   = (const float*)d_in[30];
    const float* wba   = (const float*)d_in[31];
    const float* winit = (const float*)d_in[32];
    float* ws = (float*)d_ws;

    c0<<<128, 256, 0, stream>>>(ei, pr, Wc, bc, ws);
    c1<<<165, 256, 0, stream>>>(rWk, rbk, rWb, rbb, rWg, rbg, rWs, rbs, rWgm, rbgm,
                                wWk, wbk, wWb, wbb, wWg, wbg, wWs, wbs, wWgm, wbgm,
                                wWe, wbe, wWa, wba, ws);
    c2<<<2048, 256, 0, stream>>>(M, rinit, winit, out, ws);
    c3<<<1024, 256, 0, stream>>>(out, ws);
    c4<<<1024, 256, 0, stream>>>(M, out, ws);
    c5<<<64, 256, 0, stream>>>(Wo, bo, ws, out);
}

// Round 3
// 344.702 us; speedup vs baseline: 1.2213x; 1.0137x over previous
//
#include <hip/hip_runtime.h>
#include <hip/hip_bf16.h>

#define NN 262144
#define EPS 1e-8f

typedef float f4nt __attribute__((ext_vector_type(4)));

// ---- ws layout (float offsets) ----
#define WS_C      0            // c[512]
#define WS_K      512          // k[3*128]
#define WS_E      896          // e[128]
#define WS_A      1024         // a[128]
#define WS_KNSQ   1152         // |k|^2 [3]
#define WS_BETA   1155
#define WS_G      1158
#define WS_GAMMA  1161
#define WS_SL     1164         // shift logits [3*3] -> 1173
#define WS_ZCR    1280         // 16 replicas x 32-stride: (zc0,zc1,zc2,zp0,zp1,zp2)
#define WS_SUMPR  1792         // 16 replicas x 32-stride: (sump0..2)
#define WS_RDACC  2304         // 8 replicas x 256: readings partials
#define WS_ZERO_CNT (WS_RDACC + 2048 - WS_KNSQ)   // zero 1152..4352
#define WS_T      4608         // t = exp(beta*sim) [3*NN]
#define WS_NEEDED ((size_t)(WS_T + 3 * NN) * 4)

// ---- d_out layout (FLOAT32 element offsets) ----
#define OUT_OUT   0
#define OUT_READ  256
#define OUT_RW    512
#define OUT_WW    (512 + 2 * NN)
#define OUT_MNEW  ((size_t)(512 + 3 * NN))

__global__ void FFNTM_78477642433000_kernel(int* p) { if (p) *p = 0; }

__device__ __forceinline__ float4 ld4(const float* p) { return *reinterpret_cast<const float4*>(p); }

__device__ __forceinline__ float wred(float v) {
#pragma unroll
    for (int off = 32; off > 0; off >>= 1) v += __shfl_xor(v, off);
    return v;
}

// sums the 16 ZCR replicas (c2b folded in) and builds all shift params
__device__ __forceinline__ void load_shift_params(const float* __restrict__ ws,
        float g[3], float gam[3], float izc[3], float izp[3],
        float s0[3], float s1[3], float s2[3]) {
#pragma unroll
    for (int h = 0; h < 3; h++) {
        float zc = 0.0f, zp = 0.0f;
#pragma unroll
        for (int r = 0; r < 16; r++) {
            zc += ws[WS_ZCR + r * 32 + h];
            zp += ws[WS_ZCR + r * 32 + 3 + h];
        }
        g[h]   = ws[WS_G + h];
        gam[h] = ws[WS_GAMMA + h];
        izc[h] = 1.0f / fmaxf(zc, 1e-30f);
        izp[h] = 1.0f / fmaxf(zp, 1e-30f);
        const float l0 = ws[WS_SL + h*3], l1 = ws[WS_SL + h*3 + 1], l2 = ws[WS_SL + h*3 + 2];
        const float mx = fmaxf(l0, fmaxf(l1, l2));
        const float e0 = expf(l0 - mx), e1 = expf(l1 - mx), e2 = expf(l2 - mx);
        const float inv = 1.0f / (e0 + e1 + e2);
        s0[h] = e0 * inv; s1[h] = e1 * inv; s2[h] = e2 * inv;
    }
}

__global__ void csent(float* out, float val) {
    if (threadIdx.x == 0 && blockIdx.x == 0) out[OUT_OUT] = val;
}

// ---------------- c0: controller c = Wc @ [ext, prev_read] + bc; zero accumulators
__global__ void __launch_bounds__(256) c0(const float* __restrict__ ei, const float* __restrict__ pr,
                                          const float* __restrict__ Wc, const float* __restrict__ bc,
                                          float* __restrict__ ws) {
    const int t = threadIdx.x;
    const int lane = t & 63;
    const int j = (blockIdx.x * 256 + t) >> 6;   // wave per row, 0..511

    if (blockIdx.x == 0) {
        for (int i = t; i < WS_ZERO_CNT; i += 256) ws[WS_KNSQ + i] = 0.0f;
    }

    const float* xs = (lane < 32) ? (ei + lane * 8) : (pr + (lane - 32) * 8);
    const float4 xa = ld4(xs), xb = ld4(xs + 4);
    const float* wr = Wc + j * 512 + lane * 8;
    const float4 wa = ld4(wr), wb = ld4(wr + 4);
    float acc = xa.x * wa.x + xa.y * wa.y + xa.z * wa.z + xa.w * wa.w
              + xb.x * wb.x + xb.y * wb.y + xb.z * wb.z + xb.w * wb.w;
    acc = wred(acc);
    if (lane == 0) ws[WS_C + j] = acc + bc[j];
}

// ---------------- c1: all head parameters (C-order rows)
__global__ void __launch_bounds__(256) c1(
    const float* __restrict__ rWk, const float* __restrict__ rbk,
    const float* __restrict__ rWb, const float* __restrict__ rbb,
    const float* __restrict__ rWg, const float* __restrict__ rbg,
    const float* __restrict__ rWs, const float* __restrict__ rbs,
    const float* __restrict__ rWgm, const float* __restrict__ rbgm,
    const float* __restrict__ wWk, const float* __restrict__ wbk,
    const float* __restrict__ wWb, const float* __restrict__ wbb,
    const float* __restrict__ wWg, const float* __restrict__ wbg,
    const float* __restrict__ wWs, const float* __restrict__ wbs,
    const float* __restrict__ wWgm, const float* __restrict__ wbgm,
    const float* __restrict__ wWe, const float* __restrict__ wbe,
    const float* __restrict__ wWa, const float* __restrict__ wba,
    float* __restrict__ ws) {
    const int w = blockIdx.x * 4 + (threadIdx.x >> 6);
    const int lane = threadIdx.x & 63;
    if (w >= 658) return;

    const float4 ca = ld4(ws + WS_C + lane * 8);
    const float4 cb = ld4(ws + WS_C + lane * 8 + 4);

    const float* row; float bias; int kind; int h = 0, d = 0, sidx = 0;
    if (w < 384) {                        // keys: tanh
        h = w >> 7; d = w & 127;
        row  = (h < 2) ? (rWk + (h * 128 + d) * 512) : (wWk + d * 512);
        bias = (h < 2) ? rbk[h * 128 + d] : wbk[d];
        kind = 0;
    } else if (w < 512) {                 // erase: sigmoid
        d = w - 384; row = wWe + d * 512; bias = wbe[d]; kind = 1;
    } else if (w < 640) {                 // add: tanh
        d = w - 512; row = wWa + d * 512; bias = wba[d]; kind = 2;
    } else if (w < 643) {                 // beta: softplus
        h = w - 640; row = (h < 2) ? (rWb + h * 512) : wWb;
        bias = (h < 2) ? rbb[h] : wbb[0]; kind = 3;
    } else if (w < 646) {                 // g: sigmoid
        h = w - 643; row = (h < 2) ? (rWg + h * 512) : wWg;
        bias = (h < 2) ? rbg[h] : wbg[0]; kind = 4;
    } else if (w < 649) {                 // gamma: 1+softplus
        h = w - 646; row = (h < 2) ? (rWgm + h * 512) : wWgm;
        bias = (h < 2) ? rbgm[h] : wbgm[0]; kind = 5;
    } else {                              // shift logits
        sidx = w - 649; h = sidx / 3; const int jj = sidx % 3;
        row  = (h < 2) ? (rWs + (h * 3 + jj) * 512) : (wWs + jj * 512);
        bias = (h < 2) ? rbs[h * 3 + jj] : wbs[jj];
        kind = 6;
    }

    const float4 ra = ld4(row + lane * 8);
    const float4 rb = ld4(row + lane * 8 + 4);
    float acc = ca.x * ra.x + ca.y * ra.y + ca.z * ra.z + ca.w * ra.w
              + cb.x * rb.x + cb.y * rb.y + cb.z * rb.z + cb.w * rb.w;
    acc = wred(acc);

    if (lane == 0) {
        const float x = acc + bias;
        switch (kind) {
            case 0: { float kv = tanhf(x); ws[WS_K + w] = kv; atomicAdd(&ws[WS_KNSQ + h], kv * kv); } break;
            case 1: ws[WS_E + d] = 1.0f / (1.0f + expf(-x)); break;
            case 2: ws[WS_A + d] = tanhf(x); break;
            case 3: ws[WS_BETA + h] = log1pf(expf(x)); break;
            case 4: ws[WS_G + h] = 1.0f / (1.0f + expf(-x)); break;
            case 5: ws[WS_GAMMA + h] = 1.0f + log1pf(expf(x)); break;
            case 6: ws[WS_SL + sidx] = x; break;
        }
    }
}

// ---------------- c2: content scores t=exp(beta*cos_sim); exp(init) scratch; denom partials
// 8 lanes per row (16 contiguous floats each). M loads stay CACHED (re-read by c4);
// rinit/winit loads are NON-TEMPORAL (never re-read after Esc materialized).
__global__ void __launch_bounds__(256) c2(const float* __restrict__ M, const float* __restrict__ rinit,
                                          const float* __restrict__ winit, float* __restrict__ out,
                                          float* __restrict__ ws) {
    const int t = threadIdx.x;
    const int lane = t & 63;
    const int wv = t >> 6;           // wave in block, 0..3
    const int rl = lane >> 3;        // row within wave's batch of 8
    const int cl = lane & 7;         // 16-float column slice

    float kf0[16], kf1[16], kf2[16];
#pragma unroll
    for (int j = 0; j < 16; j++) {
        kf0[j] = ws[WS_K +       cl * 16 + j];
        kf1[j] = ws[WS_K + 128 + cl * 16 + j];
        kf2[j] = ws[WS_K + 256 + cl * 16 + j];
    }
    float beta[3], kn[3];
#pragma unroll
    for (int h = 0; h < 3; h++) { kn[h] = sqrtf(ws[WS_KNSQ + h]); beta[h] = ws[WS_BETA + h]; }

    float zc0 = 0, zc1 = 0, zc2 = 0, zp0 = 0, zp1 = 0, zp2 = 0;

    // block covers 32 rows per iteration (4 waves x 8 rows)
    for (int row = blockIdx.x * 32 + wv * 8 + rl; row < NN; row += gridDim.x * 32) {
        const float* mp = M + (size_t)row * 128 + cl * 16;
        float d0 = 0, d1 = 0, d2 = 0, ns = 0;
#pragma unroll
        for (int q = 0; q < 4; q++) {
            const float4 m = ld4(mp + q * 4);
            d0 += m.x * kf0[q*4+0] + m.y * kf0[q*4+1] + m.z * kf0[q*4+2] + m.w * kf0[q*4+3];
            d1 += m.x * kf1[q*4+0] + m.y * kf1[q*4+1] + m.z * kf1[q*4+2] + m.w * kf1[q*4+3];
            d2 += m.x * kf2[q*4+0] + m.y * kf2[q*4+1] + m.z * kf2[q*4+2] + m.w * kf2[q*4+3];
            ns += m.x * m.x + m.y * m.y + m.z * m.z + m.w * m.w;
        }
#pragma unroll
        for (int off = 1; off < 8; off <<= 1) {
            d0 += __shfl_xor(d0, off);
            d1 += __shfl_xor(d1, off);
            d2 += __shfl_xor(d2, off);
            ns += __shfl_xor(ns, off);
        }
        if (cl == 0) {
            const float mn = sqrtf(ns);
            const float t0 = expf(beta[0] * d0 / (mn * kn[0] + EPS));
            const float t1 = expf(beta[1] * d1 / (mn * kn[1] + EPS));
            const float t2 = expf(beta[2] * d2 / (mn * kn[2] + EPS));
            ws[WS_T + row]          = t0;
            ws[WS_T + NN + row]     = t1;
            ws[WS_T + 2 * NN + row] = t2;
            zc0 += t0; zc1 += t1; zc2 += t2;
        }
    }

    // prev-weighting exps: compute once, STORE for c3 (scratch inside out's M_new region)
    float* Esc = out + OUT_MNEW;
    for (int i = blockIdx.x * 256 + t; i < NN; i += gridDim.x * 256) {
        const float e0 = expf(__builtin_nontemporal_load(rinit + i));
        const float e1 = expf(__builtin_nontemporal_load(rinit + NN + i));
        const float e2 = expf(__builtin_nontemporal_load(winit + i));
        Esc[i]          = e0;
        Esc[NN + i]     = e1;
        Esc[2 * NN + i] = e2;
        zp0 += e0; zp1 += e1; zp2 += e2;
    }

    __shared__ float red[4][6];
    float vals[6] = {zc0, zc1, zc2, zp0, zp1, zp2};
#pragma unroll
    for (int q = 0; q < 6; q++) {
        float v = wred(vals[q]);
        if (lane == 0) red[wv][q] = v;
    }
    __syncthreads();
    if (t < 6) {
        // padded replica slot (bid&15): 128B apart -> no same-line pileup
        atomicAdd(&ws[WS_ZCR + (blockIdx.x & 15) * 32 + t],
                  red[0][t] + red[1][t] + red[2][t] + red[3][t]);
    }
}

// ---------------- c3: sharpened unnormalized weights p -> out slots; sharpen-sum partials
__global__ void __launch_bounds__(256) c3(float* __restrict__ out, float* __restrict__ ws) {
    float g[3], gam[3], izc[3], izp[3], s0[3], s1[3], s2[3];
    load_shift_params(ws, g, gam, izc, izp, s0, s1, s2);
    const float* Esc = out + OUT_MNEW;

    float sump[3] = {0.f, 0.f, 0.f};
    for (int i = blockIdx.x * 256 + threadIdx.x; i < NN; i += gridDim.x * 256) {
        const int im = (i == 0) ? (NN - 1) : (i - 1);
        const int ip = (i == NN - 1) ? 0 : (i + 1);
#pragma unroll
        for (int h = 0; h < 3; h++) {
            const float* tp = ws + WS_T + h * NN;
            const float* Ep = Esc + (size_t)h * NN;
            const float gg = g[h], om = 1.0f - gg;
            const float wgm = gg * tp[im] * izc[h] + om * Ep[im] * izp[h];
            const float wg0 = gg * tp[i]  * izc[h] + om * Ep[i]  * izp[h];
            const float wgp = gg * tp[ip] * izc[h] + om * Ep[ip] * izp[h];
            const float wt = fmaxf(s0[h] * wgp + s1[h] * wg0 + s2[h] * wgm, 1e-30f);
            const float p = expf(gam[h] * logf(wt));
            sump[h] += p;
            float* pd = (h == 0) ? (out + OUT_RW) : (h == 1) ? (out + OUT_RW + NN) : (out + OUT_WW);
            pd[i] = p;   // unnormalized; c4 rescales in place (cached: re-read by c4)
        }
    }

    __shared__ float red[4][3];
    const int lane = threadIdx.x & 63, wv = threadIdx.x >> 6;
#pragma unroll
    for (int h = 0; h < 3; h++) {
        float v = wred(sump[h]);
        if (lane == 0) red[wv][h] = v;
    }
    __syncthreads();
    if (threadIdx.x < 3) {
        atomicAdd(&ws[WS_SUMPR + (blockIdx.x & 15) * 32 + threadIdx.x],
                  red[0][threadIdx.x] + red[1][threadIdx.x] + red[2][threadIdx.x] + red[3][threadIdx.x]);
    }
}

// ---------------- c4: pure streaming — normalize weights in place, M_new, readings partials
// ALL stores non-temporal: M_new / final weights are never re-read on device, and cached
// stores would LRU-evict the not-yet-read tail of M from L3 (write stream chasing read stream).
__global__ void __launch_bounds__(256) c4(const float* __restrict__ M, float* __restrict__ out,
                                          float* __restrict__ ws) {
    float isp[3];
#pragma unroll
    for (int h = 0; h < 3; h++) {
        float s = 0.0f;
#pragma unroll
        for (int r = 0; r < 16; r++) s += ws[WS_SUMPR + r * 32 + h];
        isp[h] = 1.0f / (s + EPS);
    }

    const int t = threadIdx.x;
    const int lane = t & 63;
    const int wv = t >> 6;
    const int grp = t >> 5;
    const int sub = lane & 31;

    float ev[4], av[4];
#pragma unroll
    for (int j = 0; j < 4; j++) { ev[j] = ws[WS_E + sub * 4 + j]; av[j] = ws[WS_A + sub * 4 + j]; }

    float r0[4] = {0, 0, 0, 0}, r1[4] = {0, 0, 0, 0};

    for (int row = blockIdx.x * 8 + grp; row < NN; row += gridDim.x * 8) {
        // broadcast loads (same address across the 32-lane group)
        const float w0 = out[OUT_RW + row]      * isp[0];
        const float w1 = out[OUT_RW + NN + row] * isp[1];
        const float w2 = out[OUT_WW + row]      * isp[2];
        const float4 m = ld4(M + (size_t)row * 128 + sub * 4);
        f4nt nv;
        nv.x = m.x * (1.0f - w2 * ev[0]) + w2 * av[0];
        nv.y = m.y * (1.0f - w2 * ev[1]) + w2 * av[1];
        nv.z = m.z * (1.0f - w2 * ev[2]) + w2 * av[2];
        nv.w = m.w * (1.0f - w2 * ev[3]) + w2 * av[3];
        __builtin_nontemporal_store(nv, reinterpret_cast<f4nt*>(out + OUT_MNEW + (size_t)row * 128 + sub * 4));
        r0[0] += w0 * m.x; r0[1] += w0 * m.y; r0[2] += w0 * m.z; r0[3] += w0 * m.w;
        r1[0] += w1 * m.x; r1[1] += w1 * m.y; r1[2] += w1 * m.z; r1[3] += w1 * m.w;
        if (sub == 0) {
            __builtin_nontemporal_store(w0, out + OUT_RW + row);
            __builtin_nontemporal_store(w1, out + OUT_RW + NN + row);
            __builtin_nontemporal_store(w2, out + OUT_WW + row);
        }
    }

#pragma unroll
    for (int j = 0; j < 4; j++) {
        r0[j] += __shfl_xor(r0[j], 32);
        r1[j] += __shfl_xor(r1[j], 32);
    }
    __shared__ float lds[4][256];
    if (lane < 32) {
#pragma unroll
        for (int j = 0; j < 4; j++) {
            lds[wv][sub * 4 + j]       = r0[j];
            lds[wv][128 + sub * 4 + j] = r1[j];
        }
    }
    __syncthreads();
    atomicAdd(&ws[WS_RDACC + (blockIdx.x & 7) * 256 + t],
              lds[0][t] + lds[1][t] + lds[2][t] + lds[3][t]);
}

// ---------------- c5: out = Wo @ [c, readings] + bo; emit readings (f32)
__global__ void __launch_bounds__(256) c5(const float* __restrict__ Wo, const float* __restrict__ bo,
                                          float* __restrict__ ws, float* __restrict__ out) {
    __shared__ float rd[256];
    const int t = threadIdx.x;
    {
        float s = 0.0f;
#pragma unroll
        for (int r = 0; r < 8; r++) s += ws[WS_RDACC + r * 256 + t];
        rd[t] = s;
    }
    __syncthreads();

    const int lane = t & 63;
    const int j = blockIdx.x * 4 + (t >> 6);   // 0..255
    const float* row = Wo + j * 768;
    float acc = 0.0f;
#pragma unroll
    for (int q = 0; q < 12; q++) {
        const int i = lane * 12 + q;
        const float x = (i < 512) ? ws[WS_C + i] : rd[i - 512];
        acc += row[i] * x;
    }
    acc = wred(acc);
    if (lane == 0) out[OUT_OUT + j] = acc + bo[j];
    if (blockIdx.x == 0) out[OUT_READ + t] = rd[t];
}

extern "C" void kernel_launch(void* const* d_in, const int* in_sizes, int n_in,
                              void* d_out, int out_size, void* d_ws, size_t ws_size,
                              hipStream_t stream) {
    float* out = (float*)d_out;

    static const int expect[33] = {
        256, 33554432, 256, 262144, 512, 196608, 256,
        131072, 256, 1024, 2, 1024, 2, 3072, 6, 1024, 2, 524288,
        65536, 128, 512, 1, 512, 1, 1536, 3, 512, 1,
        65536, 128, 65536, 128, 262144
    };
    int bad = (n_in == 33) ? -1 : 33;
    if (bad < 0) {
        for (int i = 0; i < 33; i++) {
            if (in_sizes[i] != expect[i]) { bad = i; break; }
        }
    }
    if (bad >= 0) { csent<<<1, 64, 0, stream>>>(out, 10000.0f + (float)bad); return; }
    if (ws_size < WS_NEEDED) { csent<<<1, 64, 0, stream>>>(out, 5000.0f + (float)(ws_size >> 20)); return; }

    const float* ei    = (const float*)d_in[0];
    const float* M     = (const float*)d_in[1];
    const float* pr    = (const float*)d_in[2];
    const float* Wc    = (const float*)d_in[3];
    const float* bc    = (const float*)d_in[4];
    const float* Wo    = (const float*)d_in[5];
    const float* bo    = (const float*)d_in[6];
    const float* rWk   = (const float*)d_in[7];
    const float* rbk   = (const float*)d_in[8];
    const float* rWb   = (const float*)d_in[9];
    const float* rbb   = (const float*)d_in[10];
    const float* rWg   = (const float*)d_in[11];
    const float* rbg   = (const float*)d_in[12];
    const float* rWs   = (const float*)d_in[13];
    const float* rbs   = (const float*)d_in[14];
    const float* rWgm  = (const float*)d_in[15];
    const float* rbgm  = (const float*)d_in[16];
    const float* rinit = (const float*)d_in[17];
    const float* wWk   = (const float*)d_in[18];
    const float* wbk   = (const float*)d_in[19];
    const float* wWb   = (const float*)d_in[20];
    const float* wbb   = (const float*)d_in[21];
    const float* wWg   = (const float*)d_in[22];
    const float* wbg   = (const float*)d_in[23];
    const float* wWs   = (const float*)d_in[24];
    const float* wbs   = (const float*)d_in[25];
    const float* wWgm  = (const float*)d_in[26];
    const float* wbgm  = (const float*)d_in[27];
    const float* wWe   = (const float*)d_in[28];
    const float* wbe   = (const float*)d_in[29];
    const float* wWa   = (const float*)d_in[30];
    const float* wba   = (const float*)d_in[31];
    const float* winit = (const float*)d_in[32];
    float* ws = (float*)d_ws;

    c0<<<128, 256, 0, stream>>>(ei, pr, Wc, bc, ws);
    c1<<<165, 256, 0, stream>>>(rWk, rbk, rWb, rbb, rWg, rbg, rWs, rbs, rWgm, rbgm,
                                wWk, wbk, wWb, wbb, wWg, wbg, wWs, wbs, wWgm, wbgm,
                                wWe, wbe, wWa, wba, ws);
    c2<<<2048, 256, 0, stream>>>(M, rinit, winit, out, ws);
    c3<<<1024, 256, 0, stream>>>(out, ws);
    c4<<<1024, 256, 0, stream>>>(M, out, ws);
    c5<<<64, 256, 0, stream>>>(Wo, bo, ws, out);
}